// Round 3
// baseline (38.280 us; speedup 1.0000x reference)
//
#include <hip/hip_runtime.h>

// Problem constants (from reference setup_inputs)
#define BS    128
#define CH    8
#define NSC   3276
#define TSYM  14
#define NRE   12
#define HB_STRIDE (CH*NSC)            // h_hat batch stride = 26208
#define NK    168                     // 14*12  (pattern period in r = f*14+t)
#define Q4_PER_B 91728                // float4s per batch in h_out (3276*14*8/4)
#define N4H   (BS*Q4_PER_B)           // 11,741,184 float4s (h_out)
#define PE4   22932                   // pe float4 count (3276*14*2/4)
#define PE_BLOCKS 12
#define BLK_PER_B 13                  // 13 blocks/batch; each: 7 iters x 504 r
#define HOUT_BLOCKS (BS*BLK_PER_B)    // 1664
#define R_ACTIVE 504                  // 3 pattern periods; threads 504..511 idle
#define R_PER_BLK 3528                // 7 * 504  (= 21*168)

__global__ __launch_bounds__(512)
void k_fused(const float* __restrict__ h_hat,
             const int* __restrict__ sym_pos,
             const int* __restrict__ sc_pos,
             float4* __restrict__ out)
{
    const int tid = threadIdx.x;
    const int bid = blockIdx.x;

    __shared__ int s_sc[6], s_sym[2];
    __shared__ int s_nn[NK];

    if (tid < 6) s_sc[tid]  = sc_pos[tid];
    if (tid < 2) s_sym[tid] = sym_pos[tid];
    __syncthreads();

    // nn table in flat argmin order (k = r*14 + t), pe distances in registers
    float d0f = 0.f, d1f = 0.f;
    if (tid < NK) {
        int r = tid / TSYM, t = tid % TSYM;
        int best = 1 << 30, bestm = 0, min0 = 1 << 30, min1 = 1 << 30;
        #pragma unroll
        for (int m = 0; m < 12; ++m) {
            int i = m >> 1, j = m & 1;            // pp[m] = (sc[i], sym[j])
            int d0 = abs(r - s_sc[i]);
            int d1 = abs(t - s_sym[j]);
            int d  = d0 + d1;
            if (d < best) { best = d; bestm = m; }  // first-tie-wins
            if (d0 < min0) min0 = d0;
            if (d1 < min1) min1 = d1;
        }
        s_nn[tid] = bestm;
        d0f = (float)min0;
        d1f = (float)min1;
    }

    if (bid < HOUT_BLOCKS) {
        // ---- h_out fill: one block per (batch, 1/13th of batch) ----
        const int b = bid / BLK_PER_B, blk = bid % BLK_PER_B;
        __shared__ float s_v[12];
        __shared__ float s_w2[NK];   // s_w2[(f%12)*14 + t] = v[nn[t, f%12]]
        if (tid < 12) {
            const float* hb = h_hat + (size_t)b * HB_STRIDE;   // ch 0, tx 0
            s_v[tid] = 0.5f * (hb[6 * tid] + hb[6 * tid + 1]); // focc mean
        }
        __syncthreads();
        if (tid < NK) {
            int jj = tid / TSYM, tt = tid % TSYM;
            // reference reads nn at reshaped (t, j) = flat t*12 + j
            s_w2[tid] = s_v[s_nn[tt * NRE + jj]];
        }
        __syncthreads();

        if (tid < R_ACTIVE) {
            // fixed per-thread value: rm = r % 168 is loop-invariant
            float v = s_w2[tid % NK];
            float4 v4 = make_float4(v, v, v, v);
            float4* p = out + (size_t)b * Q4_PER_B
                            + (size_t)(blk * R_PER_BLK + tid) * 2;
            #pragma unroll
            for (int it = 0; it < 7; ++it) {
                p[0] = v4;             // r-unit = 32B = two float4 stores
                p[1] = v4;
                p += 2 * R_ACTIVE;     // 16,128 B stride
            }
        }
    } else {
        // ---- pe fill: 12 blocks ----
        __shared__ float s_pe[2][NK];
        __shared__ float s_ms[4];        // mean0, mean1, rstd0, rstd1
        if (tid < NK) { s_pe[0][tid] = d0f; s_pe[1][tid] = d1f; }
        __syncthreads();

        const int wv = tid >> 6, ln = tid & 63;
        if (wv < 2) {
            float sum = 0.f;
            for (int k = ln; k < NK; k += 64) sum += s_pe[wv][k];
            for (int o = 32; o > 0; o >>= 1) sum += __shfl_down(sum, o, 64);
            if (ln == 0) s_ms[wv] = sum / (float)NK;
        }
        __syncthreads();
        if (wv < 2) {
            float mean = s_ms[wv];
            float ss = 0.f;
            for (int k = ln; k < NK; k += 64) {
                float d = s_pe[wv][k] - mean;
                ss += d * d;
            }
            for (int o = 32; o > 0; o >>= 1) ss += __shfl_down(ss, o, 64);
            if (ln == 0) {
                float sd = sqrtf(ss / (float)(NK - 1));   // ddof=1
                s_ms[2 + wv] = (sd > 0.f) ? (1.f / sd) : 1.f;
            }
        }
        __syncthreads();

        __shared__ float s_pen[336];     // pe pattern [j*28 + a*2 + e]
        if (tid < NK) {
            int a = tid / NRE, j = tid % NRE;   // flat k -> (a, j) reshape
            s_pen[(j * TSYM + a) * 2 + 0] = (s_pe[0][tid] - s_ms[0]) * s_ms[2];
            s_pen[(j * TSYM + a) * 2 + 1] = (s_pe[1][tid] - s_ms[1]) * s_ms[3];
        }
        __syncthreads();

        const float4* pen4 = (const float4*)s_pen;   // 84 float4s
        const int pb = bid - HOUT_BLOCKS;            // 0..11
        for (int qp = pb * 512 + tid; qp < PE4; qp += PE_BLOCKS * 512) {
            out[N4H + qp] = pen4[qp % 84u];
        }
    }
}

extern "C" void kernel_launch(void* const* d_in, const int* in_sizes, int n_in,
                              void* d_out, int out_size, void* d_ws, size_t ws_size,
                              hipStream_t stream) {
    const float* h_hat = (const float*)d_in[1];
    const int*   sym   = (const int*)d_in[2];
    const int*   sc    = (const int*)d_in[3];
    hipLaunchKernelGGL(k_fused, dim3(HOUT_BLOCKS + PE_BLOCKS), dim3(512), 0, stream,
                       h_hat, sym, sc, (float4*)d_out);
}

// Round 4
// 33.920 us; speedup vs baseline: 1.1285x; 1.1285x over previous
//
#include <hip/hip_runtime.h>

// Problem constants (from reference setup_inputs)
#define BS    128
#define CH    8
#define NSC   3276
#define TSYM  14
#define NRE   12
#define HB_STRIDE (CH*NSC)            // h_hat batch stride = 26208
#define NK    168                     // 14*12 (pattern period in r = f*14+t)
#define Q4_PER_B 91728                // float4s per batch in h_out (= 1008*91)
#define N4H   (BS*Q4_PER_B)           // 11,741,184 float4s (h_out)
#define PE4   22932                   // pe float4 count (3276*14*2/4)
#define PE_BLOCKS 12
#define BLK_PER_B 13                  // 13 blocks/batch
#define ITERS 7                       // 7 iters x 1008 float4s = 7056/block
#define CHUNK 1008                    // 3 pattern periods (2 stores x 512 thr)
#define HOUT_BLOCKS (BS*BLK_PER_B)    // 1664

__global__ __launch_bounds__(512)
void k_fused(const float* __restrict__ h_hat,
             const int* __restrict__ sym_pos,
             const int* __restrict__ sc_pos,
             float4* __restrict__ out)
{
    const int tid = threadIdx.x;
    const int bid = blockIdx.x;

    __shared__ int s_sc[6], s_sym[2];
    __shared__ int s_nn[NK];

    if (tid < 6) s_sc[tid]  = sc_pos[tid];
    if (tid < 2) s_sym[tid] = sym_pos[tid];
    __syncthreads();

    // nn table in flat argmin order (k = r*14 + t), pe distances in registers
    float d0f = 0.f, d1f = 0.f;
    if (tid < NK) {
        int r = tid / TSYM, t = tid % TSYM;
        int best = 1 << 30, bestm = 0, min0 = 1 << 30, min1 = 1 << 30;
        #pragma unroll
        for (int m = 0; m < 12; ++m) {
            int i = m >> 1, j = m & 1;            // pp[m] = (sc[i], sym[j])
            int d0 = abs(r - s_sc[i]);
            int d1 = abs(t - s_sym[j]);
            int d  = d0 + d1;
            if (d < best) { best = d; bestm = m; }  // first-tie-wins
            if (d0 < min0) min0 = d0;
            if (d1 < min1) min1 = d1;
        }
        s_nn[tid] = bestm;
        d0f = (float)min0;
        d1f = (float)min1;
    }

    if (bid >= PE_BLOCKS) {
        // ---- h_out fill: one block per (batch, 1/13th of batch) ----
        const int hb_id = bid - PE_BLOCKS;
        const int b = hb_id / BLK_PER_B, blk = hb_id % BLK_PER_B;
        __shared__ float s_v[12];
        __shared__ float s_w2[NK];   // s_w2[(f%12)*14 + t] = v[nn[t, f%12]]
        if (tid < 12) {
            const float* hb = h_hat + (size_t)b * HB_STRIDE;   // ch 0, tx 0
            s_v[tid] = 0.5f * (hb[6 * tid] + hb[6 * tid + 1]); // focc mean
        }
        __syncthreads();
        if (tid < NK) {
            int jj = tid / TSYM, tt = tid % TSYM;
            // reference reads nn at reshaped (t, j) = flat t*12 + j
            s_w2[tid] = s_v[s_nn[tt * NRE + jj]];
        }
        __syncthreads();

        // Per-thread loop-invariant values:
        //   float4 residue res mod 336 -> value s_w2[res>>1]
        const int res1 = tid % 336;              // store-0 residue
        const int res2 = (512 + tid) % 336;      // store-1 residue
        const float va = s_w2[res1 >> 1];
        const float vb = s_w2[res2 >> 1];
        const float4 v4a = make_float4(va, va, va, va);
        const float4 v4b = make_float4(vb, vb, vb, vb);

        float4* p = out + (size_t)b * Q4_PER_B + (size_t)blk * (ITERS * CHUNK);
        #pragma unroll
        for (int it = 0; it < ITERS; ++it) {
            p[tid] = v4a;                        // 512 contiguous float4s
            if (tid < CHUNK - 512)               // 496 contiguous float4s
                p[512 + tid] = v4b;
            p += CHUNK;
        }
    } else {
        // ---- pe fill: 12 blocks ----
        __shared__ float s_pe[2][NK];
        __shared__ float s_ms[4];        // mean0, mean1, rstd0, rstd1
        if (tid < NK) { s_pe[0][tid] = d0f; s_pe[1][tid] = d1f; }
        __syncthreads();

        const int wv = tid >> 6, ln = tid & 63;
        if (wv < 2) {
            float sum = 0.f;
            for (int k = ln; k < NK; k += 64) sum += s_pe[wv][k];
            for (int o = 32; o > 0; o >>= 1) sum += __shfl_down(sum, o, 64);
            if (ln == 0) s_ms[wv] = sum / (float)NK;
        }
        __syncthreads();
        if (wv < 2) {
            float mean = s_ms[wv];
            float ss = 0.f;
            for (int k = ln; k < NK; k += 64) {
                float d = s_pe[wv][k] - mean;
                ss += d * d;
            }
            for (int o = 32; o > 0; o >>= 1) ss += __shfl_down(ss, o, 64);
            if (ln == 0) {
                float sd = sqrtf(ss / (float)(NK - 1));   // ddof=1
                s_ms[2 + wv] = (sd > 0.f) ? (1.f / sd) : 1.f;
            }
        }
        __syncthreads();

        __shared__ float s_pen[336];     // pe pattern [j*28 + a*2 + e]
        if (tid < NK) {
            int a = tid / NRE, j = tid % NRE;   // flat k -> (a, j) reshape
            s_pen[(j * TSYM + a) * 2 + 0] = (s_pe[0][tid] - s_ms[0]) * s_ms[2];
            s_pen[(j * TSYM + a) * 2 + 1] = (s_pe[1][tid] - s_ms[1]) * s_ms[3];
        }
        __syncthreads();

        const float4* pen4 = (const float4*)s_pen;   // 84 float4s
        for (int qp = bid * 512 + tid; qp < PE4; qp += PE_BLOCKS * 512) {
            out[N4H + qp] = pen4[qp % 84u];
        }
    }
}

extern "C" void kernel_launch(void* const* d_in, const int* in_sizes, int n_in,
                              void* d_out, int out_size, void* d_ws, size_t ws_size,
                              hipStream_t stream) {
    const float* h_hat = (const float*)d_in[1];
    const int*   sym   = (const int*)d_in[2];
    const int*   sc    = (const int*)d_in[3];
    hipLaunchKernelGGL(k_fused, dim3(HOUT_BLOCKS + PE_BLOCKS), dim3(512), 0, stream,
                       h_hat, sym, sc, (float4*)d_out);
}

// Round 5
// 33.747 us; speedup vs baseline: 1.1343x; 1.0051x over previous
//
#include <hip/hip_runtime.h>

// Problem constants (from reference setup_inputs)
#define BS    128
#define CH    8
#define NSC   3276
#define TSYM  14
#define NRE   12
#define HB_STRIDE (CH*NSC)            // h_hat batch stride = 26208
#define NK    168                     // 14*12 (pattern period in r = f*14+t)
#define Q4_PER_B 91728                // float4s per batch in h_out (= 1008*91)
#define N4H   (BS*Q4_PER_B)           // 11,741,184 float4s (h_out)
#define PE4   22932                   // pe float4 count (3276*14*2/4)
#define PE_BLOCKS 12
#define CHUNK 1008                    // 1 unit = 3 pattern periods (512+496 thr)
#define BLK_PER_B 26                  // 13 blocks x 4 units + 13 blocks x 3 units
#define HOUT_BLOCKS (BS*BLK_PER_B)    // 3328

__global__ __launch_bounds__(512)
void k_fused(const float* __restrict__ h_hat,
             const int* __restrict__ sym_pos,
             const int* __restrict__ sc_pos,
             float4* __restrict__ out)
{
    const int tid = threadIdx.x;
    const int bid = blockIdx.x;

    __shared__ int s_sc[6], s_sym[2];
    __shared__ int s_nn[NK];

    if (tid < 6) s_sc[tid]  = sc_pos[tid];
    if (tid < 2) s_sym[tid] = sym_pos[tid];
    __syncthreads();

    // nn table in flat argmin order (k = r*14 + t), pe distances in registers
    float d0f = 0.f, d1f = 0.f;
    if (tid < NK) {
        int r = tid / TSYM, t = tid % TSYM;
        int best = 1 << 30, bestm = 0, min0 = 1 << 30, min1 = 1 << 30;
        #pragma unroll
        for (int m = 0; m < 12; ++m) {
            int i = m >> 1, j = m & 1;            // pp[m] = (sc[i], sym[j])
            int d0 = abs(r - s_sc[i]);
            int d1 = abs(t - s_sym[j]);
            int d  = d0 + d1;
            if (d < best) { best = d; bestm = m; }  // first-tie-wins
            if (d0 < min0) min0 = d0;
            if (d1 < min1) min1 = d1;
        }
        s_nn[tid] = bestm;
        d0f = (float)min0;
        d1f = (float)min1;
    }

    if (bid >= PE_BLOCKS) {
        // ---- h_out fill: 26 blocks per batch (13x4 + 13x3 units) ----
        const int hb_id = bid - PE_BLOCKS;
        const int b = hb_id / BLK_PER_B, blk = hb_id % BLK_PER_B;
        __shared__ float s_v[12];
        __shared__ float s_w2[NK];   // s_w2[(f%12)*14 + t] = v[nn[t, f%12]]
        if (tid < 12) {
            const float* hb = h_hat + (size_t)b * HB_STRIDE;   // ch 0, tx 0
            s_v[tid] = 0.5f * (hb[6 * tid] + hb[6 * tid + 1]); // focc mean
        }
        __syncthreads();
        if (tid < NK) {
            int jj = tid / TSYM, tt = tid % TSYM;
            // reference reads nn at reshaped (t, j) = flat t*12 + j
            s_w2[tid] = s_v[s_nn[tt * NRE + jj]];
        }
        __syncthreads();

        // Per-thread loop-invariant values (block start is a multiple of 1008)
        const int res1 = tid % 336;              // store-0 residue (float4)
        const int res2 = (512 + tid) % 336;      // store-1 residue
        const float va = s_w2[res1 >> 1];
        const float vb = s_w2[res2 >> 1];
        const float4 v4a = make_float4(va, va, va, va);
        const float4 v4b = make_float4(vb, vb, vb, vb);

        const int start_unit = (blk < 13) ? (blk * 4) : (52 + (blk - 13) * 3);
        float4* p = out + (size_t)b * Q4_PER_B + (size_t)start_unit * CHUNK;

        if (blk < 13) {
            #pragma unroll
            for (int it = 0; it < 4; ++it) {
                p[tid] = v4a;                    // 512 contiguous float4s
                if (tid < CHUNK - 512)           // 496 contiguous float4s
                    p[512 + tid] = v4b;
                p += CHUNK;
            }
        } else {
            #pragma unroll
            for (int it = 0; it < 3; ++it) {
                p[tid] = v4a;
                if (tid < CHUNK - 512)
                    p[512 + tid] = v4b;
                p += CHUNK;
            }
        }
    } else {
        // ---- pe fill: 12 blocks ----
        __shared__ float s_pe[2][NK];
        __shared__ float s_ms[4];        // mean0, mean1, rstd0, rstd1
        if (tid < NK) { s_pe[0][tid] = d0f; s_pe[1][tid] = d1f; }
        __syncthreads();

        const int wv = tid >> 6, ln = tid & 63;
        if (wv < 2) {
            float sum = 0.f;
            for (int k = ln; k < NK; k += 64) sum += s_pe[wv][k];
            for (int o = 32; o > 0; o >>= 1) sum += __shfl_down(sum, o, 64);
            if (ln == 0) s_ms[wv] = sum / (float)NK;
        }
        __syncthreads();
        if (wv < 2) {
            float mean = s_ms[wv];
            float ss = 0.f;
            for (int k = ln; k < NK; k += 64) {
                float d = s_pe[wv][k] - mean;
                ss += d * d;
            }
            for (int o = 32; o > 0; o >>= 1) ss += __shfl_down(ss, o, 64);
            if (ln == 0) {
                float sd = sqrtf(ss / (float)(NK - 1));   // ddof=1
                s_ms[2 + wv] = (sd > 0.f) ? (1.f / sd) : 1.f;
            }
        }
        __syncthreads();

        __shared__ float s_pen[336];     // pe pattern [j*28 + a*2 + e]
        if (tid < NK) {
            int a = tid / NRE, j = tid % NRE;   // flat k -> (a, j) reshape
            s_pen[(j * TSYM + a) * 2 + 0] = (s_pe[0][tid] - s_ms[0]) * s_ms[2];
            s_pen[(j * TSYM + a) * 2 + 1] = (s_pe[1][tid] - s_ms[1]) * s_ms[3];
        }
        __syncthreads();

        const float4* pen4 = (const float4*)s_pen;   // 84 float4s
        for (int qp = bid * 512 + tid; qp < PE4; qp += PE_BLOCKS * 512) {
            out[N4H + qp] = pen4[qp % 84u];
        }
    }
}

extern "C" void kernel_launch(void* const* d_in, const int* in_sizes, int n_in,
                              void* d_out, int out_size, void* d_ws, size_t ws_size,
                              hipStream_t stream) {
    const float* h_hat = (const float*)d_in[1];
    const int*   sym   = (const int*)d_in[2];
    const int*   sc    = (const int*)d_in[3];
    hipLaunchKernelGGL(k_fused, dim3(HOUT_BLOCKS + PE_BLOCKS), dim3(512), 0, stream,
                       h_hat, sym, sc, (float4*)d_out);
}